// Round 1
// baseline (826.610 us; speedup 1.0000x reference)
//
#include <hip/hip_runtime.h>
#include <hip/hip_bf16.h>

#define EPS 1e-5f
#define DIMH 128
#define K1 320
#define K3 256

typedef __attribute__((ext_vector_type(8))) short bf16x8;
typedef __attribute__((ext_vector_type(4))) short bf16x4;
typedef __attribute__((ext_vector_type(4))) float f32x4;

#define MFMA(a, b, c) __builtin_amdgcn_mfma_f32_16x16x32_bf16(a, b, c, 0, 0, 0)

static __device__ __forceinline__ unsigned short f2bf(float f) {
    union { float f; unsigned u; } v; v.f = f;
    unsigned r = v.u + 0x7FFF + ((v.u >> 16) & 1);
    return (unsigned short)(r >> 16);
}
static __device__ __forceinline__ float bf2f(unsigned short u) {
    union { unsigned u; float f; } v; v.u = ((unsigned)u) << 16;
    return v.f;
}

// ---------------- weight prep: fp32 [K][128] -> bf16 transposed [128][K] ----
__global__ void k_prep(const float* __restrict__ W1, const float* __restrict__ W2,
                       const float* __restrict__ W3, const float* __restrict__ W4,
                       unsigned short* __restrict__ W1t, unsigned short* __restrict__ W2t,
                       unsigned short* __restrict__ W3t, unsigned short* __restrict__ W4t) {
    int t = blockIdx.x * 256 + threadIdx.x;
    if (t < K1 * 128) { int k = t / 128, n = t % 128; W1t[n * K1 + k] = f2bf(W1[t]); }
    if (t < 128 * 128) { int k = t / 128, n = t % 128; W2t[n * 128 + k] = f2bf(W2[t]); }
    if (t < K3 * 128) { int k = t / 128, n = t % 128; W3t[n * K3 + k] = f2bf(W3[t]); }
    if (t < 128 * 128) { int k = t / 128, n = t % 128; W4t[n * 128 + k] = f2bf(W4[t]); }
}

// ---------------- BN params: s = g*rsqrt(var+eps), t = be - mean*s ----------
__global__ void k_bn(const float* __restrict__ stats, const float* __restrict__ g,
                     const float* __restrict__ be, float* __restrict__ st, float cnt) {
    int c = threadIdx.x;
    float mean = stats[c] / cnt;
    float var = stats[128 + c] / cnt - mean * mean;
    float s = g[c] * rsqrtf(var + EPS);
    st[c] = s;
    st[128 + c] = be[c] - mean * s;
}

// ---------------- edge GEMM1: x = [h_src|h_dst|e] @ W1 + b1, stats ----------
__global__ __launch_bounds__(256, 2) void k_msg1(
    const float* __restrict__ h, const float* __restrict__ ea,
    const int* __restrict__ src, const int* __restrict__ dst,
    const unsigned short* __restrict__ W1t, const float* __restrict__ b1,
    unsigned short* __restrict__ xout, float* __restrict__ stats) {
    const int LDA = K1 + 8;                       // 328 halves: 2-way bank alias (free)
    __shared__ unsigned short A[64 * (K1 + 8)];   // 41984 B
    int tid = threadIdx.x, lane = tid & 63, w = tid >> 6;
    long e0 = (long)blockIdx.x * 64;

    // B fragments (W1t) in registers: 10 ksteps x 2 ntiles
    bf16x8 bfr[10][2];
    {
        int n = (w << 5) + (lane & 15), kb = (lane >> 4) << 3;
#pragma unroll
        for (int nt = 0; nt < 2; ++nt) {
            const unsigned short* p = W1t + (size_t)(n + nt * 16) * K1 + kb;
#pragma unroll
            for (int ks = 0; ks < 10; ++ks) bfr[ks][nt] = *(const bf16x8*)(p + ks * 32);
        }
    }
    // stage A tile: 16 threads/row, gather + fp32->bf16
    {
        int c16 = tid & 15, r2 = tid >> 4;
#pragma unroll
        for (int rr = 0; rr < 4; ++rr) {
            int row = rr * 16 + r2;
            long e = e0 + row;
            const float* hs = h + (size_t)src[e] * DIMH;
            const float* hd = h + (size_t)dst[e] * DIMH;
            const float* ep = ea + (size_t)e * 64;
#pragma unroll
            for (int i = 0; i < 5; ++i) {
                int col = (c16 + (i << 4)) << 2;  // 0..316 step 4
                float4 v;
                if (col < 128) v = *(const float4*)(hs + col);
                else if (col < 256) v = *(const float4*)(hd + col - 128);
                else v = *(const float4*)(ep + col - 256);
                union { bf16x4 v4; unsigned short s[4]; } u;
                u.s[0] = f2bf(v.x); u.s[1] = f2bf(v.y); u.s[2] = f2bf(v.z); u.s[3] = f2bf(v.w);
                *(bf16x4*)&A[row * LDA + col] = u.v4;
            }
        }
    }
    __syncthreads();

    f32x4 acc[4][2] = {};
#pragma unroll
    for (int rg = 0; rg < 4; ++rg) {
        int ab = (rg * 16 + (lane & 15)) * LDA + ((lane >> 4) << 3);
#pragma unroll
        for (int ks = 0; ks < 10; ++ks) {
            bf16x8 af = *(const bf16x8*)&A[ab + ks * 32];
            acc[rg][0] = MFMA(af, bfr[ks][0], acc[rg][0]);
            acc[rg][1] = MFMA(af, bfr[ks][1], acc[rg][1]);
        }
    }
    // epilogue: +b1, store bf16 x, accumulate BN stats
    int c0 = (w << 5) + (lane & 15);
    float bias0 = b1[c0], bias1 = b1[c0 + 16];
    float ss[2] = {0.f, 0.f}, sq[2] = {0.f, 0.f};
#pragma unroll
    for (int rg = 0; rg < 4; ++rg)
#pragma unroll
        for (int r = 0; r < 4; ++r) {
            long row = e0 + rg * 16 + ((lane >> 4) << 2) + r;
            float v0 = acc[rg][0][r] + bias0;
            float v1 = acc[rg][1][r] + bias1;
            ss[0] += v0; sq[0] += v0 * v0;
            ss[1] += v1; sq[1] += v1 * v1;
            xout[(size_t)row * DIMH + c0] = f2bf(v0);
            xout[(size_t)row * DIMH + c0 + 16] = f2bf(v1);
        }
#pragma unroll
    for (int nt = 0; nt < 2; ++nt) {
        ss[nt] += __shfl_xor(ss[nt], 16); ss[nt] += __shfl_xor(ss[nt], 32);
        sq[nt] += __shfl_xor(sq[nt], 16); sq[nt] += __shfl_xor(sq[nt], 32);
    }
    if (lane < 16) {
        atomicAdd(&stats[c0], ss[0]);        atomicAdd(&stats[c0 + 16], ss[1]);
        atomicAdd(&stats[128 + c0], sq[0]);  atomicAdd(&stats[128 + c0 + 16], sq[1]);
    }
}

// ---------------- edge GEMM2: msg = relu(BN(x)) @ W2 + b2, scatter-add ------
__global__ __launch_bounds__(256, 2) void k_msg2(
    const unsigned short* __restrict__ x, const int* __restrict__ dst,
    const unsigned short* __restrict__ W2t, const float* __restrict__ b2,
    const float* __restrict__ st, float* __restrict__ agg) {
    const int LDA = 136;
    __shared__ unsigned short A[64 * 136];
    __shared__ float sS[128], sT[128];
    __shared__ int dstv[64];
    int tid = threadIdx.x, lane = tid & 63, w = tid >> 6;
    long e0 = (long)blockIdx.x * 64;
    if (tid < 128) { sS[tid] = st[tid]; sT[tid] = st[128 + tid]; }
    if (tid < 64) dstv[tid] = dst[e0 + tid];

    bf16x8 bfr[4][2];
    {
        int n = (w << 5) + (lane & 15), kb = (lane >> 4) << 3;
#pragma unroll
        for (int nt = 0; nt < 2; ++nt) {
            const unsigned short* p = W2t + (size_t)(n + nt * 16) * 128 + kb;
#pragma unroll
            for (int ks = 0; ks < 4; ++ks) bfr[ks][nt] = *(const bf16x8*)(p + ks * 32);
        }
    }
    __syncthreads();   // sS/sT ready
    {
        int c16 = tid & 15, r2 = tid >> 4;
#pragma unroll
        for (int rr = 0; rr < 4; ++rr) {
            int row = rr * 16 + r2;
            bf16x8 v = *(const bf16x8*)(x + (size_t)(e0 + row) * DIMH + c16 * 8);
            union { bf16x8 v8; unsigned short s[8]; } u;
#pragma unroll
            for (int j = 0; j < 8; ++j) {
                int c = c16 * 8 + j;
                float f = bf2f((unsigned short)v[j]) * sS[c] + sT[c];
                u.s[j] = f2bf(fmaxf(f, 0.f));
            }
            *(bf16x8*)&A[row * LDA + c16 * 8] = u.v8;
        }
    }
    __syncthreads();

    f32x4 acc[4][2] = {};
#pragma unroll
    for (int rg = 0; rg < 4; ++rg) {
        int ab = (rg * 16 + (lane & 15)) * LDA + ((lane >> 4) << 3);
#pragma unroll
        for (int ks = 0; ks < 4; ++ks) {
            bf16x8 af = *(const bf16x8*)&A[ab + ks * 32];
            acc[rg][0] = MFMA(af, bfr[ks][0], acc[rg][0]);
            acc[rg][1] = MFMA(af, bfr[ks][1], acc[rg][1]);
        }
    }
    int c0 = (w << 5) + (lane & 15);
    float bias0 = b2[c0], bias1 = b2[c0 + 16];
#pragma unroll
    for (int rg = 0; rg < 4; ++rg)
#pragma unroll
        for (int r = 0; r < 4; ++r) {
            int row = rg * 16 + ((lane >> 4) << 2) + r;
            float* ap = agg + (size_t)dstv[row] * DIMH;
            atomicAdd(ap + c0, acc[rg][0][r] + bias0);
            atomicAdd(ap + c0 + 16, acc[rg][1][r] + bias1);
        }
}

// ---------------- node GEMM1: y_pre = [h|agg] @ W3 + b3, stats --------------
__global__ __launch_bounds__(256, 2) void k_upd1(
    const float* __restrict__ h, const float* __restrict__ agg,
    const unsigned short* __restrict__ W3t, const float* __restrict__ b3,
    unsigned short* __restrict__ ypre, float* __restrict__ stats, int NN) {
    const int LDA = K3 + 8;                      // 264
    __shared__ unsigned short A[64 * (K3 + 8)];  // 33792 B
    int tid = threadIdx.x, lane = tid & 63, w = tid >> 6;
    int n0 = blockIdx.x * 64;

    bf16x8 bfr[8][2];
    {
        int n = (w << 5) + (lane & 15), kb = (lane >> 4) << 3;
#pragma unroll
        for (int nt = 0; nt < 2; ++nt) {
            const unsigned short* p = W3t + (size_t)(n + nt * 16) * K3 + kb;
#pragma unroll
            for (int ks = 0; ks < 8; ++ks) bfr[ks][nt] = *(const bf16x8*)(p + ks * 32);
        }
    }
    {
        int c16 = tid & 15, r2 = tid >> 4;
#pragma unroll
        for (int rr = 0; rr < 4; ++rr) {
            int row = rr * 16 + r2;
            int node = n0 + row;
#pragma unroll
            for (int i = 0; i < 4; ++i) {
                int col = (c16 + (i << 4)) << 2;  // 0..252
                float4 v = make_float4(0.f, 0.f, 0.f, 0.f);
                if (node < NN)
                    v = (col < 128) ? *(const float4*)(h + (size_t)node * DIMH + col)
                                    : *(const float4*)(agg + (size_t)node * DIMH + col - 128);
                union { bf16x4 v4; unsigned short s[4]; } u;
                u.s[0] = f2bf(v.x); u.s[1] = f2bf(v.y); u.s[2] = f2bf(v.z); u.s[3] = f2bf(v.w);
                *(bf16x4*)&A[row * LDA + col] = u.v4;
            }
        }
    }
    __syncthreads();

    f32x4 acc[4][2] = {};
#pragma unroll
    for (int rg = 0; rg < 4; ++rg) {
        int ab = (rg * 16 + (lane & 15)) * LDA + ((lane >> 4) << 3);
#pragma unroll
        for (int ks = 0; ks < 8; ++ks) {
            bf16x8 af = *(const bf16x8*)&A[ab + ks * 32];
            acc[rg][0] = MFMA(af, bfr[ks][0], acc[rg][0]);
            acc[rg][1] = MFMA(af, bfr[ks][1], acc[rg][1]);
        }
    }
    int c0 = (w << 5) + (lane & 15);
    float bias0 = b3[c0], bias1 = b3[c0 + 16];
    float ss[2] = {0.f, 0.f}, sq[2] = {0.f, 0.f};
#pragma unroll
    for (int rg = 0; rg < 4; ++rg)
#pragma unroll
        for (int r = 0; r < 4; ++r) {
            int node = n0 + rg * 16 + ((lane >> 4) << 2) + r;
            if (node < NN) {
                float v0 = acc[rg][0][r] + bias0;
                float v1 = acc[rg][1][r] + bias1;
                ss[0] += v0; sq[0] += v0 * v0;
                ss[1] += v1; sq[1] += v1 * v1;
                ypre[(size_t)node * DIMH + c0] = f2bf(v0);
                ypre[(size_t)node * DIMH + c0 + 16] = f2bf(v1);
            }
        }
#pragma unroll
    for (int nt = 0; nt < 2; ++nt) {
        ss[nt] += __shfl_xor(ss[nt], 16); ss[nt] += __shfl_xor(ss[nt], 32);
        sq[nt] += __shfl_xor(sq[nt], 16); sq[nt] += __shfl_xor(sq[nt], 32);
    }
    if (lane < 16) {
        atomicAdd(&stats[c0], ss[0]);        atomicAdd(&stats[c0 + 16], ss[1]);
        atomicAdd(&stats[128 + c0], sq[0]);  atomicAdd(&stats[128 + c0 + 16], sq[1]);
    }
}

// ------- node GEMM2 + residual + LayerNorm: out = LN(h + relu(BN(y))@W4+b4) -
__global__ __launch_bounds__(256, 2) void k_upd2(
    const unsigned short* __restrict__ ypre, const unsigned short* __restrict__ W4t,
    const float* __restrict__ b4, const float* __restrict__ st,
    const float* __restrict__ h, const float* __restrict__ lng,
    const float* __restrict__ lnb, float* __restrict__ out, int NN) {
    const int LDA = 136;
    __shared__ unsigned short A[64 * 136];
    __shared__ float sS[128], sT[128];
    __shared__ float rsum[64], rsq[64];
    int tid = threadIdx.x, lane = tid & 63, w = tid >> 6;
    int n0 = blockIdx.x * 64;
    if (tid < 128) { sS[tid] = st[tid]; sT[tid] = st[128 + tid]; }
    if (tid < 64) { rsum[tid] = 0.f; rsq[tid] = 0.f; }

    bf16x8 bfr[4][2];
    {
        int n = (w << 5) + (lane & 15), kb = (lane >> 4) << 3;
#pragma unroll
        for (int nt = 0; nt < 2; ++nt) {
            const unsigned short* p = W4t + (size_t)(n + nt * 16) * 128 + kb;
#pragma unroll
            for (int ks = 0; ks < 4; ++ks) bfr[ks][nt] = *(const bf16x8*)(p + ks * 32);
        }
    }
    __syncthreads();
    {
        int c16 = tid & 15, r2 = tid >> 4;
#pragma unroll
        for (int rr = 0; rr < 4; ++rr) {
            int row = rr * 16 + r2;
            int node = n0 + row;
            union { bf16x8 v8; unsigned short s[8]; } u;
            if (node < NN) {
                bf16x8 v = *(const bf16x8*)(ypre + (size_t)node * DIMH + c16 * 8);
#pragma unroll
                for (int j = 0; j < 8; ++j) {
                    int c = c16 * 8 + j;
                    float f = bf2f((unsigned short)v[j]) * sS[c] + sT[c];
                    u.s[j] = f2bf(fmaxf(f, 0.f));
                }
            } else {
#pragma unroll
                for (int j = 0; j < 8; ++j) u.s[j] = 0;
            }
            *(bf16x8*)&A[row * LDA + c16 * 8] = u.v8;
        }
    }
    __syncthreads();

    f32x4 acc[4][2] = {};
#pragma unroll
    for (int rg = 0; rg < 4; ++rg) {
        int ab = (rg * 16 + (lane & 15)) * LDA + ((lane >> 4) << 3);
#pragma unroll
        for (int ks = 0; ks < 4; ++ks) {
            bf16x8 af = *(const bf16x8*)&A[ab + ks * 32];
            acc[rg][0] = MFMA(af, bfr[ks][0], acc[rg][0]);
            acc[rg][1] = MFMA(af, bfr[ks][1], acc[rg][1]);
        }
    }
    int c0 = (w << 5) + (lane & 15);
    float bias0 = b4[c0], bias1 = b4[c0 + 16];
    float z[4][2][4];
#pragma unroll
    for (int rg = 0; rg < 4; ++rg)
#pragma unroll
        for (int r = 0; r < 4; ++r) {
            int node = n0 + rg * 16 + ((lane >> 4) << 2) + r;
            float h0 = 0.f, h1 = 0.f;
            if (node < NN) {
                h0 = h[(size_t)node * DIMH + c0];
                h1 = h[(size_t)node * DIMH + c0 + 16];
            }
            z[rg][0][r] = acc[rg][0][r] + bias0 + h0;
            z[rg][1][r] = acc[rg][1][r] + bias1 + h1;
        }
    // per-row LayerNorm stats: reduce 32 cols in-wave, combine 4 waves in LDS
#pragma unroll
    for (int rg = 0; rg < 4; ++rg)
#pragma unroll
        for (int r = 0; r < 4; ++r) {
            float ps = z[rg][0][r] + z[rg][1][r];
            float pq = z[rg][0][r] * z[rg][0][r] + z[rg][1][r] * z[rg][1][r];
#pragma unroll
            for (int m = 1; m < 16; m <<= 1) { ps += __shfl_xor(ps, m); pq += __shfl_xor(pq, m); }
            if ((lane & 15) == 0) {
                int row = rg * 16 + ((lane >> 4) << 2) + r;
                atomicAdd(&rsum[row], ps);
                atomicAdd(&rsq[row], pq);
            }
        }
    __syncthreads();
#pragma unroll
    for (int rg = 0; rg < 4; ++rg)
#pragma unroll
        for (int r = 0; r < 4; ++r) {
            int row = rg * 16 + ((lane >> 4) << 2) + r;
            int node = n0 + row;
            if (node < NN) {
                float mean = rsum[row] * (1.f / 128.f);
                float var = rsq[row] * (1.f / 128.f) - mean * mean;
                float rs = rsqrtf(var + EPS);
                float g0 = lng[c0], g1 = lng[c0 + 16];
                float be0 = lnb[c0], be1 = lnb[c0 + 16];
                out[(size_t)node * DIMH + c0] = (z[rg][0][r] - mean) * rs * g0 + be0;
                out[(size_t)node * DIMH + c0 + 16] = (z[rg][1][r] - mean) * rs * g1 + be1;
            }
        }
}

extern "C" void kernel_launch(void* const* d_in, const int* in_sizes, int n_in,
                              void* d_out, int out_size, void* d_ws, size_t ws_size,
                              hipStream_t stream) {
    const float* h   = (const float*)d_in[0];
    const float* ea  = (const float*)d_in[1];
    const float* W1  = (const float*)d_in[2];
    const float* b1  = (const float*)d_in[3];
    const float* g1  = (const float*)d_in[4];
    const float* be1 = (const float*)d_in[5];
    const float* W2  = (const float*)d_in[6];
    const float* b2  = (const float*)d_in[7];
    const float* W3  = (const float*)d_in[8];
    const float* b3  = (const float*)d_in[9];
    const float* g2  = (const float*)d_in[10];
    const float* be2 = (const float*)d_in[11];
    const float* W4  = (const float*)d_in[12];
    const float* b4  = (const float*)d_in[13];
    const float* lng = (const float*)d_in[14];
    const float* lnb = (const float*)d_in[15];
    const int* eidx  = (const int*)d_in[16];
    int NN = in_sizes[0] / DIMH;
    int E  = in_sizes[16] / 2;
    const int* src = eidx;
    const int* dst = eidx + E;

    char* ws = (char*)d_ws;
    unsigned short* W1t = (unsigned short*)(ws + 0);         // 81920
    unsigned short* W2t = (unsigned short*)(ws + 81920);     // 32768
    unsigned short* W3t = (unsigned short*)(ws + 114688);    // 65536
    unsigned short* W4t = (unsigned short*)(ws + 180224);    // 32768
    float* stats1 = (float*)(ws + 212992);                   // 1024
    float* st1    = (float*)(ws + 214016);                   // 1024
    float* stats2 = (float*)(ws + 215040);                   // 1024
    float* st2    = (float*)(ws + 216064);                   // 1024
    unsigned short* x = (unsigned short*)(ws + 217088);      // E*128*2 = 163840000
    float* agg = (float*)(ws + 217088 + 163840000ULL);       // N*128*4 = 25600000
    unsigned short* ypre = (unsigned short*)(ws + 217088 + 163840000ULL + 25600000ULL);

    hipMemsetAsync(stats1, 0, 1024, stream);
    hipMemsetAsync(stats2, 0, 1024, stream);
    hipMemsetAsync(agg, 0, (size_t)NN * DIMH * sizeof(float), stream);

    k_prep<<<(K1 * 128 + 255) / 256, 256, 0, stream>>>(W1, W2, W3, W4, W1t, W2t, W3t, W4t);
    k_msg1<<<E / 64, 256, 0, stream>>>(h, ea, src, dst, W1t, b1, x, stats1);
    k_bn<<<1, 128, 0, stream>>>(stats1, g1, be1, st1, (float)E);
    k_msg2<<<E / 64, 256, 0, stream>>>(x, dst, W2t, b2, st1, agg);
    int nb = (NN + 63) / 64;
    k_upd1<<<nb, 256, 0, stream>>>(h, agg, W3t, b3, ypre, stats2, NN);
    k_bn<<<1, 128, 0, stream>>>(stats2, g2, be2, st2, (float)NN);
    k_upd2<<<nb, 256, 0, stream>>>(ypre, W4t, b4, st2, h, lng, lnb, (float*)d_out, NN);
}